// Round 12
// baseline (42.403 us; speedup 1.0000x reference)
//
#include <hip/hip_runtime.h>
#include <hip/hip_bf16.h>

typedef _Float16 f16x8 __attribute__((ext_vector_type(8)));
typedef _Float16 f16x4 __attribute__((ext_vector_type(4)));
typedef float    f32x4 __attribute__((ext_vector_type(4)));

constexpr int BB  = 4096;
constexpr int AA  = 64;
constexpr int ED  = 10;
constexpr int P1N = 32, P2N = 128, P3N = 256;
constexpr int PT  = 416;          // = 13 * 32
constexpr int NKS = 13;           // K-steps of 32
constexpr int BCH = 64;           // b rows per block
constexpr int NCH = 4;            // a-channels per block (fp16x4 per slot)

// ---------------------------------------------------------------------------
// idxs[p] = (sa*8) | (sb*8)<<10 | (sc*8)<<20  -- BYTE offsets into an f16x4
// row (8 B/slot). Unused factors -> slot 64 (constant 1.0).
// ---------------------------------------------------------------------------
__global__ void build_idx_kernel(
    const int* __restrict__ i1, const int* __restrict__ l1,
    const int* __restrict__ i2, const int* __restrict__ j2,
    const int* __restrict__ l2, const int* __restrict__ m2,
    const int* __restrict__ i3, const int* __restrict__ j3,
    const int* __restrict__ f3, const int* __restrict__ l3,
    const int* __restrict__ m3, const int* __restrict__ g3,
    unsigned* __restrict__ idxs) {
  const int p = threadIdx.x;
  if (p >= PT) return;
  unsigned sa, sb = 64, sc = 64;
  if (p < P1N) {
    sa = i1[p] * 4 + l1[p];
  } else if (p < P1N + P2N) {
    int pp = p - P1N;
    sa = i2[pp] * 4 + l2[pp];
    sb = j2[pp] * 4 + m2[pp];
  } else {
    int pp = p - P1N - P2N;
    sa = i3[pp] * 4 + l3[pp];
    sb = j3[pp] * 4 + m3[pp];
    sc = f3[pp] * 4 + g3[pp];
  }
  idxs[p] = (sa * 8) | ((sb * 8) << 10) | ((sc * 8) << 20);
}

// ---------------------------------------------------------------------------
// B-frag table (fp16): cwb[a][ks][lane][j] = f16( coeff[p] * w[e,k[p],q[p],a] )
// p = ks*32 + (lane>>4)*8 + j, e = lane&15 (0 for e>=10).
// ---------------------------------------------------------------------------
__global__ void build_cwb_kernel(
    const float* __restrict__ w1, const float* __restrict__ w2, const float* __restrict__ w3,
    const float* __restrict__ c1, const float* __restrict__ c2, const float* __restrict__ c3,
    const int* __restrict__ k1, const int* __restrict__ q1,
    const int* __restrict__ k2, const int* __restrict__ q2,
    const int* __restrict__ k3, const int* __restrict__ q3,
    _Float16* __restrict__ cwb) {
  const int a  = blockIdx.x & 63;
  const int ks = blockIdx.x >> 6;   // 0..12
  const int l  = threadIdx.x;       // 0..63
  const int grp = l >> 4, e = l & 15;
  _Float16* dst = cwb + (((size_t)a * NKS + ks) * 64 + l) * 8;
  #pragma unroll
  for (int j = 0; j < 8; ++j) {
    const int p = ks * 32 + grp * 8 + j;
    float v = 0.f;
    if (e < ED) {
      const float* w; float coeff; int k, q, K, Q;
      if (p < P1N)            { w = w1; coeff = c1[p]; k = k1[p]; q = q1[p]; K = 4;  Q = 2; }
      else if (p < P1N + P2N) { int pp = p - P1N;       w = w2; coeff = c2[pp]; k = k2[pp]; q = q2[pp]; K = 16; Q = 4; }
      else                    { int pp = p - P1N - P2N; w = w3; coeff = c3[pp]; k = k3[pp]; q = q3[pp]; K = 32; Q = 6; }
      v = coeff * w[(((size_t)e * K + k) * Q + q) * AA + a];
    }
    dst[j] = (_Float16)v;
  }
}

// ---------------------------------------------------------------------------
// Gather buffer: one half-kstep (4 p's x up to 3 factors) of f16x4 reads.
// ---------------------------------------------------------------------------
struct GBuf {
  f16x4 g0[4], g1[4], g2[4];
};

template <int NF>
__device__ __forceinline__ void issue_gather(GBuf& b, const char* __restrict__ rowb,
                                             uint4 pk) {
  const unsigned p[4] = {pk.x, pk.y, pk.z, pk.w};
  #pragma unroll
  for (int j = 0; j < 4; ++j) {
    b.g0[j] = *(const f16x4*)(rowb + (p[j] & 1023u));
    if (NF >= 2) b.g1[j] = *(const f16x4*)(rowb + ((p[j] >> 10) & 1023u));
    if (NF >= 3) b.g2[j] = *(const f16x4*)(rowb + (p[j] >> 20));
  }
}

template <int NF, int OFF>
__device__ __forceinline__ void consume(const GBuf& b,
                                        f16x8& af0, f16x8& af1, f16x8& af2, f16x8& af3) {
  #pragma unroll
  for (int j = 0; j < 4; ++j) {
    f16x4 v = b.g0[j];
    if (NF >= 2) v = v * b.g1[j];
    if (NF >= 3) v = v * b.g2[j];
    af0[OFF + j] = v[0]; af1[OFF + j] = v[1];
    af2[OFF + j] = v[2]; af3[OFF + j] = v[3];
  }
}

// ---------------------------------------------------------------------------
// One K-step with 2-stage gather pipeline. On entry:
//   bufA holds KS's first-half gathers (in flight / returned)
//   iB = idx second-half of KS; iN = idx first-half of KS+1
//   cb* = B-frags of KS
// ---------------------------------------------------------------------------
template <int KS, int NF, int NFN, bool LAST>
__device__ __forceinline__ void kstep(
    const char* __restrict__ rowb, const uint4* __restrict__ ip,
    const f16x8* __restrict__ cw0, const f16x8* __restrict__ cw1,
    const f16x8* __restrict__ cw2, const f16x8* __restrict__ cw3,
    GBuf& bufA, GBuf& bufB, uint4& iB, uint4& iN,
    f16x8& cb0, f16x8& cb1, f16x8& cb2, f16x8& cb3,
    f32x4& ac0, f32x4& ac1, f32x4& ac2, f32x4& ac3) {
  // 1. issue second half of KS (addresses ready since last kstep)
  issue_gather<NF>(bufB, rowb, iB);
  // 2. prefetch idx: iB of KS+1 (used next kstep step 1)
  if constexpr (!LAST) iB = ip[(KS + 1) * 8 + 1];
  // 3. consume first half (bufA returned; lgkmcnt leaves bufB pending)
  f16x8 af0, af1, af2, af3;
  consume<NF, 0>(bufA, af0, af1, af2, af3);
  // 4. issue first half of KS+1 (iN loaded during previous kstep)
  if constexpr (!LAST) issue_gather<NFN>(bufA, rowb, iN);
  // 5. prefetch idx: iA of KS+2 (used next kstep step 4)
  if constexpr (KS + 2 < NKS) iN = ip[(KS + 2) * 8];
  // 6. consume second half
  consume<NF, 4>(bufB, af0, af1, af2, af3);
  // 7. MFMA
  ac0 = __builtin_amdgcn_mfma_f32_16x16x32_f16(af0, cb0, ac0, 0, 0, 0);
  ac1 = __builtin_amdgcn_mfma_f32_16x16x32_f16(af1, cb1, ac1, 0, 0, 0);
  ac2 = __builtin_amdgcn_mfma_f32_16x16x32_f16(af2, cb2, ac2, 0, 0, 0);
  ac3 = __builtin_amdgcn_mfma_f32_16x16x32_f16(af3, cb3, ac3, 0, 0, 0);
  // 8. B-frags for KS+1 (consumed next kstep step 7: fully hidden)
  if constexpr (!LAST) {
    cb0 = cw0[(KS + 1) * 64];
    cb1 = cw1[(KS + 1) * 64];
    cb2 = cw2[(KS + 1) * 64];
    cb3 = cw3[(KS + 1) * 64];
  }
}

// ---------------------------------------------------------------------------
// Main: block = a-quad x 64 b's; 4 waves = 4 M-tiles. Straight-line 13
// ksteps, LDS-gather double-buffered + global idx/B-frag prefetched.
// (256,4): 128-VGPR budget; ~120 used, no spill (WRITE_SIZE sentinel).
// ---------------------------------------------------------------------------
__global__ __launch_bounds__(256, 4)
void contract_kernel(const float* __restrict__ x, const float* __restrict__ y,
                     const unsigned* __restrict__ idxs,
                     const f16x8* __restrict__ cwb,
                     float* __restrict__ out) {
  __shared__ f16x4 xls[BCH][65];   // slot 64 = {1,1,1,1}; 33.3 KB
  __shared__ float yls[BCH][17];   // e padded to 16 with zeros

  const int t  = threadIdx.x;
  const int a0 = (blockIdx.x & 15) * NCH;
  const int b0 = (blockIdx.x >> 4) * BCH;

  // Stage x: lane = slot; 4 coalesced dword loads -> cvt f16 -> one b64 write.
  for (int u = t; u < BCH * 64; u += 256) {
    const int b = u >> 6, s = u & 63;
    const float* xb = x + (size_t)(b0 + b) * 4096 + a0 * 64 + s;
    f16x4 v;
    v[0] = (_Float16)xb[0];
    v[1] = (_Float16)xb[64];
    v[2] = (_Float16)xb[128];
    v[3] = (_Float16)xb[192];
    xls[b][s] = v;
  }
  if (t < BCH) {
    f16x4 one;
    one[0] = one[1] = one[2] = one[3] = (_Float16)1.0f;
    xls[t][64] = one;
    const float* yb = y + (size_t)(b0 + t) * ED;
    #pragma unroll
    for (int e = 0; e < ED; ++e) yls[t][e] = yb[e];
    #pragma unroll
    for (int e = ED; e < 16; ++e) yls[t][e] = 0.f;
  }
  __syncthreads();

  const int wv = t >> 6, l = t & 63, grp = l >> 4, er = l & 15;
  const char* __restrict__ rowb = (const char*)&xls[wv * 16 + er][0];
  const f16x8* __restrict__ cw0 = cwb + ((size_t)(a0 + 0) * NKS) * 64 + l;
  const f16x8* __restrict__ cw1 = cwb + ((size_t)(a0 + 1) * NKS) * 64 + l;
  const f16x8* __restrict__ cw2 = cwb + ((size_t)(a0 + 2) * NKS) * 64 + l;
  const f16x8* __restrict__ cw3 = cwb + ((size_t)(a0 + 3) * NKS) * 64 + l;
  const uint4*  __restrict__ ip  = (const uint4*)idxs + grp * 2;

  f32x4 ac0 = {0.f, 0.f, 0.f, 0.f};
  f32x4 ac1 = {0.f, 0.f, 0.f, 0.f};
  f32x4 ac2 = {0.f, 0.f, 0.f, 0.f};
  f32x4 ac3 = {0.f, 0.f, 0.f, 0.f};

  // Prologue: idx for ks0 halves + ks1 first half; B-frags ks0; issue g0.
  GBuf bufA, bufB;
  uint4 iA0 = ip[0];
  uint4 iB  = ip[1];
  uint4 iN  = ip[8];
  f16x8 cb0 = cw0[0], cb1 = cw1[0], cb2 = cw2[0], cb3 = cw3[0];
  issue_gather<1>(bufA, rowb, iA0);

  #define STEP(KS, NF, NFN, LAST)                                             \
    kstep<KS, NF, NFN, LAST>(rowb, ip, cw0, cw1, cw2, cw3, bufA, bufB,        \
                             iB, iN, cb0, cb1, cb2, cb3, ac0, ac1, ac2, ac3)
  STEP(0, 1, 2, false);
  STEP(1, 2, 2, false);
  STEP(2, 2, 2, false);
  STEP(3, 2, 2, false);
  STEP(4, 2, 3, false);
  STEP(5, 3, 3, false);
  STEP(6, 3, 3, false);
  STEP(7, 3, 3, false);
  STEP(8, 3, 3, false);
  STEP(9, 3, 3, false);
  STEP(10, 3, 3, false);
  STEP(11, 3, 3, false);
  STEP(12, 3, 3, true);
  #undef STEP

  // Epilogue: D[row = grp*4+v][col = er], y-weight, 16-lane reduce over e.
  #pragma unroll
  for (int c = 0; c < NCH; ++c) {
    const f32x4 acc = c == 0 ? ac0 : c == 1 ? ac1 : c == 2 ? ac2 : ac3;
    float s0 = acc[0] * yls[wv * 16 + grp * 4 + 0][er];
    float s1 = acc[1] * yls[wv * 16 + grp * 4 + 1][er];
    float s2 = acc[2] * yls[wv * 16 + grp * 4 + 2][er];
    float s3 = acc[3] * yls[wv * 16 + grp * 4 + 3][er];
    #pragma unroll
    for (int m = 1; m < 16; m <<= 1) {
      s0 += __shfl_xor(s0, m);
      s1 += __shfl_xor(s1, m);
      s2 += __shfl_xor(s2, m);
      s3 += __shfl_xor(s3, m);
    }
    if (er < 4) {
      const float sv = er == 0 ? s0 : er == 1 ? s1 : er == 2 ? s2 : s3;
      out[(size_t)(b0 + wv * 16 + grp * 4 + er) * AA + (a0 + c)] = sv;
    }
  }
}

// ---------------------------------------------------------------------------
extern "C" void kernel_launch(void* const* d_in, const int* in_sizes, int n_in,
                              void* d_out, int out_size, void* d_ws, size_t ws_size,
                              hipStream_t stream) {
  const float* x  = (const float*)d_in[0];
  const float* y  = (const float*)d_in[1];
  const float* w1 = (const float*)d_in[2];
  const float* w2 = (const float*)d_in[3];
  const float* w3 = (const float*)d_in[4];
  const float* c1 = (const float*)d_in[5];
  const float* c2 = (const float*)d_in[6];
  const float* c3 = (const float*)d_in[7];
  const int* i1 = (const int*)d_in[8];
  const int* l1 = (const int*)d_in[9];
  const int* k1 = (const int*)d_in[10];
  const int* q1 = (const int*)d_in[11];
  const int* i2 = (const int*)d_in[12];
  const int* j2 = (const int*)d_in[13];
  const int* l2 = (const int*)d_in[14];
  const int* m2 = (const int*)d_in[15];
  const int* k2 = (const int*)d_in[16];
  const int* q2 = (const int*)d_in[17];
  const int* i3 = (const int*)d_in[18];
  const int* j3 = (const int*)d_in[19];
  const int* f3 = (const int*)d_in[20];
  const int* l3 = (const int*)d_in[21];
  const int* m3 = (const int*)d_in[22];
  const int* g3 = (const int*)d_in[23];
  const int* k3 = (const int*)d_in[24];
  const int* q3 = (const int*)d_in[25];

  unsigned*  idxs = (unsigned*)d_ws;                    // 416*4 B
  _Float16*  cwb  = (_Float16*)((char*)d_ws + 4096);    // 832 KB

  build_idx_kernel<<<1, 448, 0, stream>>>(i1, l1, i2, j2, l2, m2,
                                          i3, j3, f3, l3, m3, g3, idxs);
  build_cwb_kernel<<<AA * NKS, 64, 0, stream>>>(w1, w2, w3, c1, c2, c3,
                                                k1, q1, k2, q2, k3, q3, cwb);
  contract_kernel<<<(AA / NCH) * (BB / BCH), 256, 0, stream>>>(
      x, y, idxs, (const f16x8*)cwb, (float*)d_out);
}

// Round 13
// 39.845 us; speedup vs baseline: 1.0642x; 1.0642x over previous
//
#include <hip/hip_runtime.h>
#include <hip/hip_bf16.h>

typedef _Float16 f16x8 __attribute__((ext_vector_type(8)));
typedef _Float16 f16x4 __attribute__((ext_vector_type(4)));
typedef float    f32x4 __attribute__((ext_vector_type(4)));

constexpr int BB  = 4096;
constexpr int AA  = 64;
constexpr int ED  = 10;
constexpr int P1N = 32, P2N = 128, P3N = 256;
constexpr int PT  = 416;          // = 13 * 32
constexpr int NKS = 13;           // K-steps of 32
constexpr int BCH = 64;           // b rows per block
constexpr int NCH = 4;            // a-channels per block (fp16x4 per slot)

// ---------------------------------------------------------------------------
// idxs[p] = (sa*8) | (sb*8)<<10 | (sc*8)<<20  -- BYTE offsets into an f16x4
// row (8 B/slot). Unused factors -> slot 64 (constant 1.0).
// ---------------------------------------------------------------------------
__global__ void build_idx_kernel(
    const int* __restrict__ i1, const int* __restrict__ l1,
    const int* __restrict__ i2, const int* __restrict__ j2,
    const int* __restrict__ l2, const int* __restrict__ m2,
    const int* __restrict__ i3, const int* __restrict__ j3,
    const int* __restrict__ f3, const int* __restrict__ l3,
    const int* __restrict__ m3, const int* __restrict__ g3,
    unsigned* __restrict__ idxs) {
  const int p = threadIdx.x;
  if (p >= PT) return;
  unsigned sa, sb = 64, sc = 64;
  if (p < P1N) {
    sa = i1[p] * 4 + l1[p];
  } else if (p < P1N + P2N) {
    int pp = p - P1N;
    sa = i2[pp] * 4 + l2[pp];
    sb = j2[pp] * 4 + m2[pp];
  } else {
    int pp = p - P1N - P2N;
    sa = i3[pp] * 4 + l3[pp];
    sb = j3[pp] * 4 + m3[pp];
    sc = f3[pp] * 4 + g3[pp];
  }
  idxs[p] = (sa * 8) | ((sb * 8) << 10) | ((sc * 8) << 20);
}

// ---------------------------------------------------------------------------
// B-frag table (fp16): cwb[a][ks][lane][j] = f16( coeff[p] * w[e,k[p],q[p],a] )
// p = ks*32 + (lane>>4)*8 + j, e = lane&15 (0 for e>=10).
// ---------------------------------------------------------------------------
__global__ void build_cwb_kernel(
    const float* __restrict__ w1, const float* __restrict__ w2, const float* __restrict__ w3,
    const float* __restrict__ c1, const float* __restrict__ c2, const float* __restrict__ c3,
    const int* __restrict__ k1, const int* __restrict__ q1,
    const int* __restrict__ k2, const int* __restrict__ q2,
    const int* __restrict__ k3, const int* __restrict__ q3,
    _Float16* __restrict__ cwb) {
  const int a  = blockIdx.x & 63;
  const int ks = blockIdx.x >> 6;   // 0..12
  const int l  = threadIdx.x;       // 0..63
  const int grp = l >> 4, e = l & 15;
  _Float16* dst = cwb + (((size_t)a * NKS + ks) * 64 + l) * 8;
  #pragma unroll
  for (int j = 0; j < 8; ++j) {
    const int p = ks * 32 + grp * 8 + j;
    float v = 0.f;
    if (e < ED) {
      const float* w; float coeff; int k, q, K, Q;
      if (p < P1N)            { w = w1; coeff = c1[p]; k = k1[p]; q = q1[p]; K = 4;  Q = 2; }
      else if (p < P1N + P2N) { int pp = p - P1N;       w = w2; coeff = c2[pp]; k = k2[pp]; q = q2[pp]; K = 16; Q = 4; }
      else                    { int pp = p - P1N - P2N; w = w3; coeff = c3[pp]; k = k3[pp]; q = q3[pp]; K = 32; Q = 6; }
      v = coeff * w[(((size_t)e * K + k) * Q + q) * AA + a];
    }
    dst[j] = (_Float16)v;
  }
}

// ---------------------------------------------------------------------------
// One K-step (r11 structure): first issue next kstep's idx + B-frag global
// loads, then gather (NF-specialized), fp16 muls -> A-frags, 4x MFMA.
// ---------------------------------------------------------------------------
template <int NF, int KS, bool LAST>
__device__ __forceinline__ void kstep(
    const char* __restrict__ rowb, const uint4* __restrict__ ip,
    const f16x8* __restrict__ cw0, const f16x8* __restrict__ cw1,
    const f16x8* __restrict__ cw2, const f16x8* __restrict__ cw3,
    uint4 iA, uint4 iB,
    f16x8 b0, f16x8 b1, f16x8 b2, f16x8 b3,
    uint4& nA, uint4& nB,
    f16x8& n0, f16x8& n1, f16x8& n2, f16x8& n3,
    f32x4& ac0, f32x4& ac1, f32x4& ac2, f32x4& ac3) {
  if constexpr (!LAST) {
    nA = ip[(KS + 1) * 8];
    nB = ip[(KS + 1) * 8 + 1];
    n0 = cw0[(KS + 1) * 64];
    n1 = cw1[(KS + 1) * 64];
    n2 = cw2[(KS + 1) * 64];
    n3 = cw3[(KS + 1) * 64];
  }
  const unsigned pks[8] = {iA.x, iA.y, iA.z, iA.w, iB.x, iB.y, iB.z, iB.w};
  f16x8 af0, af1, af2, af3;
  #pragma unroll
  for (int jh = 0; jh < 2; ++jh) {
    f16x4 g0[4], g1[4], g2[4];
    #pragma unroll
    for (int j = 0; j < 4; ++j) {
      const unsigned pk = pks[jh * 4 + j];
      g0[j] = *(const f16x4*)(rowb + (pk & 1023u));
      if (NF >= 2) g1[j] = *(const f16x4*)(rowb + ((pk >> 10) & 1023u));
      if (NF >= 3) g2[j] = *(const f16x4*)(rowb + (pk >> 20));
    }
    #pragma unroll
    for (int j = 0; j < 4; ++j) {
      f16x4 v = g0[j];
      if (NF >= 2) v = v * g1[j];
      if (NF >= 3) v = v * g2[j];
      const int jj = jh * 4 + j;
      af0[jj] = v[0]; af1[jj] = v[1]; af2[jj] = v[2]; af3[jj] = v[3];
    }
  }
  ac0 = __builtin_amdgcn_mfma_f32_16x16x32_f16(af0, b0, ac0, 0, 0, 0);
  ac1 = __builtin_amdgcn_mfma_f32_16x16x32_f16(af1, b1, ac1, 0, 0, 0);
  ac2 = __builtin_amdgcn_mfma_f32_16x16x32_f16(af2, b2, ac2, 0, 0, 0);
  ac3 = __builtin_amdgcn_mfma_f32_16x16x32_f16(af3, b3, ac3, 0, 0, 0);
}

// ---------------------------------------------------------------------------
// Main: block = a-quad x 64 b's; 4 waves = 4 M-tiles, each FULLY PRIVATE:
// wave wv stages ONLY rows [wv*16, wv*16+16) of xls/yls and gathers only
// from them -> NO __syncthreads anywhere. Staging of one wave overlaps
// compute of others; waves de-convoy naturally.
// (256,4): 128-VGPR budget, no spill (WRITE_SIZE sentinel).
// ---------------------------------------------------------------------------
__global__ __launch_bounds__(256, 4)
void contract_kernel(const float* __restrict__ x, const float* __restrict__ y,
                     const unsigned* __restrict__ idxs,
                     const f16x8* __restrict__ cwb,
                     float* __restrict__ out) {
  __shared__ f16x4 xls[BCH][65];   // slot 64 = {1,1,1,1}; 33.3 KB
  __shared__ float yls[BCH][17];   // e padded to 16 with zeros

  const int t  = threadIdx.x;
  const int a0 = (blockIdx.x & 15) * NCH;
  const int b0 = (blockIdx.x >> 4) * BCH;
  const int wv = t >> 6, l = t & 63, grp = l >> 4, er = l & 15;
  const int r0 = wv * 16;          // this wave's private row base

  // Per-wave staging of its own 16 rows: lane = slot, 4 coalesced dword
  // loads per row -> cvt f16 -> one ds_write_b64.
  #pragma unroll 4
  for (int r = 0; r < 16; ++r) {
    const int row = r0 + r;
    const float* xb = x + (size_t)(b0 + row) * 4096 + a0 * 64 + l;
    f16x4 v;
    v[0] = (_Float16)xb[0];
    v[1] = (_Float16)xb[64];
    v[2] = (_Float16)xb[128];
    v[3] = (_Float16)xb[192];
    xls[row][l] = v;
  }
  if (l < 16) {
    f16x4 one;
    one[0] = one[1] = one[2] = one[3] = (_Float16)1.0f;
    xls[r0 + l][64] = one;
    const float* yb = y + (size_t)(b0 + r0 + l) * ED;
    #pragma unroll
    for (int e = 0; e < ED; ++e) yls[r0 + l][e] = yb[e];
    #pragma unroll
    for (int e = ED; e < 16; ++e) yls[r0 + l][e] = 0.f;
  }
  // NO __syncthreads: wave reads only its own writes; compiler inserts the
  // lgkmcnt wait for the write->read hazard within the wave.

  const char* __restrict__ rowb = (const char*)&xls[r0 + er][0];
  const f16x8* __restrict__ cw0 = cwb + ((size_t)(a0 + 0) * NKS) * 64 + l;
  const f16x8* __restrict__ cw1 = cwb + ((size_t)(a0 + 1) * NKS) * 64 + l;
  const f16x8* __restrict__ cw2 = cwb + ((size_t)(a0 + 2) * NKS) * 64 + l;
  const f16x8* __restrict__ cw3 = cwb + ((size_t)(a0 + 3) * NKS) * 64 + l;
  const uint4*  __restrict__ ip  = (const uint4*)idxs + grp * 2;

  f32x4 ac0 = {0.f, 0.f, 0.f, 0.f};
  f32x4 ac1 = {0.f, 0.f, 0.f, 0.f};
  f32x4 ac2 = {0.f, 0.f, 0.f, 0.f};
  f32x4 ac3 = {0.f, 0.f, 0.f, 0.f};

  // Prologue: kstep 0's idx + B-frags (no barrier above -> these global
  // loads can hoist and hide under staging).
  uint4 cA = ip[0], cB = ip[1];
  f16x8 cb0 = cw0[0], cb1 = cw1[0], cb2 = cw2[0], cb3 = cw3[0];

  #define STEP(NF, KS, LAST)                                                  \
    kstep<NF, KS, LAST>(rowb, ip, cw0, cw1, cw2, cw3, cA, cB,                 \
                        cb0, cb1, cb2, cb3, cA, cB, cb0, cb1, cb2, cb3,       \
                        ac0, ac1, ac2, ac3)
  STEP(1, 0, false);                                      // path 1
  STEP(2, 1, false); STEP(2, 2, false);                   // path 2
  STEP(2, 3, false); STEP(2, 4, false);
  STEP(3, 5, false); STEP(3, 6, false); STEP(3, 7, false);  // path 3
  STEP(3, 8, false); STEP(3, 9, false); STEP(3, 10, false);
  STEP(3, 11, false); STEP(3, 12, true);
  #undef STEP

  // Epilogue: D[row = grp*4+v][col = er], y-weight, 16-lane reduce over e.
  #pragma unroll
  for (int c = 0; c < NCH; ++c) {
    const f32x4 acc = c == 0 ? ac0 : c == 1 ? ac1 : c == 2 ? ac2 : ac3;
    float s0 = acc[0] * yls[r0 + grp * 4 + 0][er];
    float s1 = acc[1] * yls[r0 + grp * 4 + 1][er];
    float s2 = acc[2] * yls[r0 + grp * 4 + 2][er];
    float s3 = acc[3] * yls[r0 + grp * 4 + 3][er];
    #pragma unroll
    for (int m = 1; m < 16; m <<= 1) {
      s0 += __shfl_xor(s0, m);
      s1 += __shfl_xor(s1, m);
      s2 += __shfl_xor(s2, m);
      s3 += __shfl_xor(s3, m);
    }
    if (er < 4) {
      const float sv = er == 0 ? s0 : er == 1 ? s1 : er == 2 ? s2 : s3;
      out[(size_t)(b0 + r0 + grp * 4 + er) * AA + (a0 + c)] = sv;
    }
  }
}

// ---------------------------------------------------------------------------
extern "C" void kernel_launch(void* const* d_in, const int* in_sizes, int n_in,
                              void* d_out, int out_size, void* d_ws, size_t ws_size,
                              hipStream_t stream) {
  const float* x  = (const float*)d_in[0];
  const float* y  = (const float*)d_in[1];
  const float* w1 = (const float*)d_in[2];
  const float* w2 = (const float*)d_in[3];
  const float* w3 = (const float*)d_in[4];
  const float* c1 = (const float*)d_in[5];
  const float* c2 = (const float*)d_in[6];
  const float* c3 = (const float*)d_in[7];
  const int* i1 = (const int*)d_in[8];
  const int* l1 = (const int*)d_in[9];
  const int* k1 = (const int*)d_in[10];
  const int* q1 = (const int*)d_in[11];
  const int* i2 = (const int*)d_in[12];
  const int* j2 = (const int*)d_in[13];
  const int* l2 = (const int*)d_in[14];
  const int* m2 = (const int*)d_in[15];
  const int* k2 = (const int*)d_in[16];
  const int* q2 = (const int*)d_in[17];
  const int* i3 = (const int*)d_in[18];
  const int* j3 = (const int*)d_in[19];
  const int* f3 = (const int*)d_in[20];
  const int* l3 = (const int*)d_in[21];
  const int* m3 = (const int*)d_in[22];
  const int* g3 = (const int*)d_in[23];
  const int* k3 = (const int*)d_in[24];
  const int* q3 = (const int*)d_in[25];

  unsigned*  idxs = (unsigned*)d_ws;                    // 416*4 B
  _Float16*  cwb  = (_Float16*)((char*)d_ws + 4096);    // 832 KB

  build_idx_kernel<<<1, 448, 0, stream>>>(i1, l1, i2, j2, l2, m2,
                                          i3, j3, f3, l3, m3, g3, idxs);
  build_cwb_kernel<<<AA * NKS, 64, 0, stream>>>(w1, w2, w3, c1, c2, c3,
                                                k1, q1, k2, q2, k3, q3, cwb);
  contract_kernel<<<(AA / NCH) * (BB / BCH), 256, 0, stream>>>(
      x, y, idxs, (const f16x8*)cwb, (float*)d_out);
}

// Round 14
// 38.823 us; speedup vs baseline: 1.0922x; 1.0263x over previous
//
#include <hip/hip_runtime.h>
#include <hip/hip_bf16.h>

typedef _Float16 f16x8 __attribute__((ext_vector_type(8)));
typedef _Float16 f16x4 __attribute__((ext_vector_type(4)));
typedef float    f32x4 __attribute__((ext_vector_type(4)));

constexpr int BB  = 4096;
constexpr int AA  = 64;
constexpr int ED  = 10;
constexpr int P1N = 32, P2N = 128, P3N = 256;
constexpr int PT  = 416;          // = 13 * 32
constexpr int NKS = 13;           // K-steps of 32
constexpr int BCH = 64;           // b rows per block
constexpr int NCH = 4;            // a-channels per block (fp16x4 per slot)

// ---------------------------------------------------------------------------
// idxs[p] = (sa*8) | (sb*8)<<10 | (sc*8)<<20  -- BYTE offsets into an f16x4
// row (8 B/slot). Unused factors -> slot 64 (constant 1.0).
// ---------------------------------------------------------------------------
__global__ void build_idx_kernel(
    const int* __restrict__ i1, const int* __restrict__ l1,
    const int* __restrict__ i2, const int* __restrict__ j2,
    const int* __restrict__ l2, const int* __restrict__ m2,
    const int* __restrict__ i3, const int* __restrict__ j3,
    const int* __restrict__ f3, const int* __restrict__ l3,
    const int* __restrict__ m3, const int* __restrict__ g3,
    unsigned* __restrict__ idxs) {
  const int p = threadIdx.x;
  if (p >= PT) return;
  unsigned sa, sb = 64, sc = 64;
  if (p < P1N) {
    sa = i1[p] * 4 + l1[p];
  } else if (p < P1N + P2N) {
    int pp = p - P1N;
    sa = i2[pp] * 4 + l2[pp];
    sb = j2[pp] * 4 + m2[pp];
  } else {
    int pp = p - P1N - P2N;
    sa = i3[pp] * 4 + l3[pp];
    sb = j3[pp] * 4 + m3[pp];
    sc = f3[pp] * 4 + g3[pp];
  }
  idxs[p] = (sa * 8) | ((sb * 8) << 10) | ((sc * 8) << 20);
}

// ---------------------------------------------------------------------------
// B-frag table (fp16): cwb[a][ks][lane][j] = f16( coeff[p] * w[e,k[p],q[p],a] )
// p = ks*32 + (lane>>4)*8 + j, e = lane&15 (0 for e>=10).
// ---------------------------------------------------------------------------
__global__ void build_cwb_kernel(
    const float* __restrict__ w1, const float* __restrict__ w2, const float* __restrict__ w3,
    const float* __restrict__ c1, const float* __restrict__ c2, const float* __restrict__ c3,
    const int* __restrict__ k1, const int* __restrict__ q1,
    const int* __restrict__ k2, const int* __restrict__ q2,
    const int* __restrict__ k3, const int* __restrict__ q3,
    _Float16* __restrict__ cwb) {
  const int a  = blockIdx.x & 63;
  const int ks = blockIdx.x >> 6;   // 0..12
  const int l  = threadIdx.x;       // 0..63
  const int grp = l >> 4, e = l & 15;
  _Float16* dst = cwb + (((size_t)a * NKS + ks) * 64 + l) * 8;
  #pragma unroll
  for (int j = 0; j < 8; ++j) {
    const int p = ks * 32 + grp * 8 + j;
    float v = 0.f;
    if (e < ED) {
      const float* w; float coeff; int k, q, K, Q;
      if (p < P1N)            { w = w1; coeff = c1[p]; k = k1[p]; q = q1[p]; K = 4;  Q = 2; }
      else if (p < P1N + P2N) { int pp = p - P1N;       w = w2; coeff = c2[pp]; k = k2[pp]; q = q2[pp]; K = 16; Q = 4; }
      else                    { int pp = p - P1N - P2N; w = w3; coeff = c3[pp]; k = k3[pp]; q = q3[pp]; K = 32; Q = 6; }
      v = coeff * w[(((size_t)e * K + k) * Q + q) * AA + a];
    }
    dst[j] = (_Float16)v;
  }
}

// ---------------------------------------------------------------------------
// One K-step, PURE SSA: loads its own idx/B-frags directly (no carried
// state -> no cross-kstep register recurrence; the scheduler is free to
// hoist later ksteps' loads into earlier ksteps' stall shadows).
// ---------------------------------------------------------------------------
template <int NF, int KS>
__device__ __forceinline__ void kstep(
    const char* __restrict__ rowb, const uint4* __restrict__ ip,
    const f16x8* __restrict__ cw0, const f16x8* __restrict__ cw1,
    const f16x8* __restrict__ cw2, const f16x8* __restrict__ cw3,
    f32x4& ac0, f32x4& ac1, f32x4& ac2, f32x4& ac3) {
  const uint4 iA = ip[KS * 8 + 0];
  const uint4 iB = ip[KS * 8 + 1];
  const f16x8 b0 = cw0[KS * 64];
  const f16x8 b1 = cw1[KS * 64];
  const f16x8 b2 = cw2[KS * 64];
  const f16x8 b3 = cw3[KS * 64];
  const unsigned pks[8] = {iA.x, iA.y, iA.z, iA.w, iB.x, iB.y, iB.z, iB.w};
  f16x8 af0, af1, af2, af3;
  #pragma unroll
  for (int jh = 0; jh < 2; ++jh) {
    f16x4 g0[4], g1[4], g2[4];
    #pragma unroll
    for (int j = 0; j < 4; ++j) {
      const unsigned pk = pks[jh * 4 + j];
      g0[j] = *(const f16x4*)(rowb + (pk & 1023u));
      if (NF >= 2) g1[j] = *(const f16x4*)(rowb + ((pk >> 10) & 1023u));
      if (NF >= 3) g2[j] = *(const f16x4*)(rowb + (pk >> 20));
    }
    #pragma unroll
    for (int j = 0; j < 4; ++j) {
      f16x4 v = g0[j];
      if (NF >= 2) v = v * g1[j];
      if (NF >= 3) v = v * g2[j];
      const int jj = jh * 4 + j;
      af0[jj] = v[0]; af1[jj] = v[1]; af2[jj] = v[2]; af3[jj] = v[3];
    }
  }
  ac0 = __builtin_amdgcn_mfma_f32_16x16x32_f16(af0, b0, ac0, 0, 0, 0);
  ac1 = __builtin_amdgcn_mfma_f32_16x16x32_f16(af1, b1, ac1, 0, 0, 0);
  ac2 = __builtin_amdgcn_mfma_f32_16x16x32_f16(af2, b2, ac2, 0, 0, 0);
  ac3 = __builtin_amdgcn_mfma_f32_16x16x32_f16(af3, b3, ac3, 0, 0, 0);
}

// ---------------------------------------------------------------------------
// Main: block = a-quad x 64 b's; 4 waves = 4 fully private M-tiles (no
// __syncthreads). float4 staging: 16 x4-loads/thread instead of 64 scalar.
// Straight-line SSA ksteps. (256,4): 128-VGPR budget (WRITE_SIZE sentinel).
// ---------------------------------------------------------------------------
__global__ __launch_bounds__(256, 4)
void contract_kernel(const float* __restrict__ x, const float* __restrict__ y,
                     const unsigned* __restrict__ idxs,
                     const f16x8* __restrict__ cwb,
                     float* __restrict__ out) {
  __shared__ f16x4 xls[BCH][65];   // slot 64 = {1,1,1,1}; 33.3 KB
  __shared__ float yls[BCH][17];   // e padded to 16 with zeros

  const int t  = threadIdx.x;
  const int a0 = (blockIdx.x & 15) * NCH;
  const int b0 = (blockIdx.x >> 4) * BCH;
  const int wv = t >> 6, l = t & 63, grp = l >> 4, er = l & 15;
  const int r0 = wv * 16;          // this wave's private row base

  // Per-wave staging: iteration i covers rows r0+i*4 .. +3; lane l handles
  // row r0+i*4+(l>>4), slots 4*(l&15)..+3. Four float4 loads (one per
  // channel), cvt+transpose to 4 f16x4 slots, 32B contiguous LDS write.
  #pragma unroll
  for (int i = 0; i < 4; ++i) {
    const int row = r0 + i * 4 + (l >> 4);
    const int s   = (l & 15) * 4;
    const float* xb = x + (size_t)(b0 + row) * 4096 + a0 * 64 + s;
    const float4 L0 = *(const float4*)(xb);
    const float4 L1 = *(const float4*)(xb + 64);
    const float4 L2 = *(const float4*)(xb + 128);
    const float4 L3 = *(const float4*)(xb + 192);
    f16x4 v0, v1, v2, v3;
    v0[0] = (_Float16)L0.x; v0[1] = (_Float16)L1.x; v0[2] = (_Float16)L2.x; v0[3] = (_Float16)L3.x;
    v1[0] = (_Float16)L0.y; v1[1] = (_Float16)L1.y; v1[2] = (_Float16)L2.y; v1[3] = (_Float16)L3.y;
    v2[0] = (_Float16)L0.z; v2[1] = (_Float16)L1.z; v2[2] = (_Float16)L2.z; v2[3] = (_Float16)L3.z;
    v3[0] = (_Float16)L0.w; v3[1] = (_Float16)L1.w; v3[2] = (_Float16)L2.w; v3[3] = (_Float16)L3.w;
    xls[row][s + 0] = v0;
    xls[row][s + 1] = v1;
    xls[row][s + 2] = v2;
    xls[row][s + 3] = v3;
  }
  if (l < 16) {
    f16x4 one;
    one[0] = one[1] = one[2] = one[3] = (_Float16)1.0f;
    xls[r0 + l][64] = one;
    const float* yb = y + (size_t)(b0 + r0 + l) * ED;
    #pragma unroll
    for (int e = 0; e < ED; ++e) yls[r0 + l][e] = yb[e];
    #pragma unroll
    for (int e = ED; e < 16; ++e) yls[r0 + l][e] = 0.f;
  }
  // NO __syncthreads: wave reads only its own writes (in-wave lgkmcnt).

  const char* __restrict__ rowb = (const char*)&xls[r0 + er][0];
  const f16x8* __restrict__ cw0 = cwb + ((size_t)(a0 + 0) * NKS) * 64 + l;
  const f16x8* __restrict__ cw1 = cwb + ((size_t)(a0 + 1) * NKS) * 64 + l;
  const f16x8* __restrict__ cw2 = cwb + ((size_t)(a0 + 2) * NKS) * 64 + l;
  const f16x8* __restrict__ cw3 = cwb + ((size_t)(a0 + 3) * NKS) * 64 + l;
  const uint4*  __restrict__ ip  = (const uint4*)idxs + grp * 2;

  f32x4 ac0 = {0.f, 0.f, 0.f, 0.f};
  f32x4 ac1 = {0.f, 0.f, 0.f, 0.f};
  f32x4 ac2 = {0.f, 0.f, 0.f, 0.f};
  f32x4 ac3 = {0.f, 0.f, 0.f, 0.f};

  #define STEP(NF, KS) \
    kstep<NF, KS>(rowb, ip, cw0, cw1, cw2, cw3, ac0, ac1, ac2, ac3)
  STEP(1, 0);                                   // path 1
  STEP(2, 1); STEP(2, 2); STEP(2, 3); STEP(2, 4);   // path 2
  STEP(3, 5); STEP(3, 6); STEP(3, 7); STEP(3, 8);   // path 3
  STEP(3, 9); STEP(3, 10); STEP(3, 11); STEP(3, 12);
  #undef STEP

  // Epilogue: D[row = grp*4+v][col = er], y-weight, 16-lane reduce over e.
  #pragma unroll
  for (int c = 0; c < NCH; ++c) {
    const f32x4 acc = c == 0 ? ac0 : c == 1 ? ac1 : c == 2 ? ac2 : ac3;
    float s0 = acc[0] * yls[r0 + grp * 4 + 0][er];
    float s1 = acc[1] * yls[r0 + grp * 4 + 1][er];
    float s2 = acc[2] * yls[r0 + grp * 4 + 2][er];
    float s3 = acc[3] * yls[r0 + grp * 4 + 3][er];
    #pragma unroll
    for (int m = 1; m < 16; m <<= 1) {
      s0 += __shfl_xor(s0, m);
      s1 += __shfl_xor(s1, m);
      s2 += __shfl_xor(s2, m);
      s3 += __shfl_xor(s3, m);
    }
    if (er < 4) {
      const float sv = er == 0 ? s0 : er == 1 ? s1 : er == 2 ? s2 : s3;
      out[(size_t)(b0 + r0 + grp * 4 + er) * AA + (a0 + c)] = sv;
    }
  }
}

// ---------------------------------------------------------------------------
extern "C" void kernel_launch(void* const* d_in, const int* in_sizes, int n_in,
                              void* d_out, int out_size, void* d_ws, size_t ws_size,
                              hipStream_t stream) {
  const float* x  = (const float*)d_in[0];
  const float* y  = (const float*)d_in[1];
  const float* w1 = (const float*)d_in[2];
  const float* w2 = (const float*)d_in[3];
  const float* w3 = (const float*)d_in[4];
  const float* c1 = (const float*)d_in[5];
  const float* c2 = (const float*)d_in[6];
  const float* c3 = (const float*)d_in[7];
  const int* i1 = (const int*)d_in[8];
  const int* l1 = (const int*)d_in[9];
  const int* k1 = (const int*)d_in[10];
  const int* q1 = (const int*)d_in[11];
  const int* i2 = (const int*)d_in[12];
  const int* j2 = (const int*)d_in[13];
  const int* l2 = (const int*)d_in[14];
  const int* m2 = (const int*)d_in[15];
  const int* k2 = (const int*)d_in[16];
  const int* q2 = (const int*)d_in[17];
  const int* i3 = (const int*)d_in[18];
  const int* j3 = (const int*)d_in[19];
  const int* f3 = (const int*)d_in[20];
  const int* l3 = (const int*)d_in[21];
  const int* m3 = (const int*)d_in[22];
  const int* g3 = (const int*)d_in[23];
  const int* k3 = (const int*)d_in[24];
  const int* q3 = (const int*)d_in[25];

  unsigned*  idxs = (unsigned*)d_ws;                    // 416*4 B
  _Float16*  cwb  = (_Float16*)((char*)d_ws + 4096);    // 832 KB

  build_idx_kernel<<<1, 448, 0, stream>>>(i1, l1, i2, j2, l2, m2,
                                          i3, j3, f3, l3, m3, g3, idxs);
  build_cwb_kernel<<<AA * NKS, 64, 0, stream>>>(w1, w2, w3, c1, c2, c3,
                                                k1, q1, k2, q2, k3, q3, cwb);
  contract_kernel<<<(AA / NCH) * (BB / BCH), 256, 0, stream>>>(
      x, y, idxs, (const f16x8*)cwb, (float*)d_out);
}